// Round 3
// baseline (441.606 us; speedup 1.0000x reference)
//
#include <hip/hip_runtime.h>
#include <stdint.h>

typedef __attribute__((ext_vector_type(8))) short short8;
typedef __attribute__((ext_vector_type(4))) float float4v;

#define NPIX 240
#define PIXSTRIDE 68   // shorts/pixel: word-stride 34 == 2 mod 32 -> 2-way (free)
                       // LDS conflicts on both b64 writes and b64 reads

// ---- compile-time hex-padding source map (replays reference copy order) ----
struct MapT { int m[256]; };
constexpr MapT build_map() {
    MapT t{};
    int m[225] = {};
    for (int r = 0; r < 15; ++r)
        for (int c = 0; c < 15; ++c)
            m[r*15+c] = (r>=1 && r<=13 && c>=1 && c<=13) ? (r-1)*13 + (c-1) : -1;
    for (int k = 0; k < 7; ++k) m[0*15 + 1+k]      = m[12*15 + 7+k];
    for (int r = 0; r < 3; ++r) m[r*15 + 8+r]      = m[(6+r)*15 + 2+r];
    for (int r = 0; r < 4; ++r) m[(3+r)*15 + 10+r] = m[(9+r)*15 + 4+r];
    for (int r = 0; r < 3; ++r) m[(7+r)*15 + 13]   = m[(1+r)*15 + 1];
    for (int r = 0; r < 3; ++r) m[(10+r)*15 + 14]  = m[(4+r)*15 + 2];
    for (int r = 0; r < 8; ++r) m[13*15 + 7+r]     = m[1*15 + 1+r];
    for (int r = 0; r < 4; ++r) m[(9+r)*15 + 3+r]  = m[(3+r)*15 + 9+r];
    for (int r = 0; r < 3; ++r) m[(6+r)*15 + 1+r]  = m[r*15 + 7+r];
    for (int r = 0; r < 2; ++r) m[(4+r)*15 + 1]    = m[(10+r)*15 + 13];
    for (int r = 0; r < 4; ++r) m[r*15 + 0]        = m[(6+r)*15 + 12];
    for (int i = 0;   i < 225; ++i) t.m[i] = m[i];
    for (int i = 225; i < 256; ++i) t.m[i] = -1;
    return t;
}
__device__ __constant__ MapT c_map = build_map();

// ---- compile-time output mask ----
struct OmT { float v[169]; };
constexpr OmT build_om() {
    OmT t{};
    for (int i = 0; i < 169; ++i) t.v[i] = 1.f;
    for (int i = 0; i < 5; ++i) for (int j = 8+i; j < 13; ++j) t.v[i*13+j] = 0.f;
    for (int i = 0; i < 4; ++i) t.v[(2+i)*13 + 9+i] = 0.f;
    for (int i = 6; i < 9; ++i) t.v[i*13 + 12] = 0.f;
    for (int i = 0; i < 6; ++i) for (int j = 0; j <= i; ++j) t.v[(6+i)*13 + j] = 0.f;
    for (int i = 0; i < 3; ++i) t.v[(5+i)*13 + i] = 0.f;
    t.v[3*13] = 0.f; t.v[4*13] = 0.f;
    return t;
}
__device__ __constant__ OmT c_om = build_om();

__device__ __forceinline__ unsigned short f2bf_rne(float f) {
    union { float f; unsigned u; } v; v.f = f;
    unsigned r = v.u + 0x7FFFu + ((v.u >> 16) & 1u);
    return (unsigned short)(r >> 16);
}

// fragment-ordered bf16 weights in ws: item = (ct*14 + ks)*64 + lane, 8 bf16 each
__global__ void hex_prep_kernel(const float* __restrict__ w,
                                unsigned short* __restrict__ wsA) {
    const int gid = blockIdx.x * blockDim.x + threadIdx.x;
    const int nthr = gridDim.x * blockDim.x;
    const int ti_tab[7] = {0,0,1,1,1,2,2};
    const int tj_tab[7] = {0,1,0,1,2,1,2};
    for (int item = gid; item < 4*14*64; item += nthr) {
        int lane = item & 63;
        int ks   = (item >> 6) % 14;
        int ct   = (item >> 6) / 14;
        int co = ct*16 + (lane & 15);
        int k0 = ks*32 + (lane >> 4)*8;
        unsigned short vals[8];
        #pragma unroll
        for (int j = 0; j < 8; ++j) {
            int k = k0 + j;
            int tap = k >> 6, ci = k & 63;
            vals[j] = f2bf_rne(w[(co*64 + ci)*9 + ti_tab[tap]*3 + tj_tab[tap]]);
        }
        for (int j = 0; j < 8; ++j) wsA[item*8 + j] = vals[j];
    }
}

// wave w: ctp = w&1 -> co-tiles {2ctp, 2ctp+1}; nth = w>>1 -> nt = nth*7 + j.
// A-fragments flow through a 1-step software prefetch (32 VGPRs in flight),
// so the MFMA loop never waits on L2.
__global__ __launch_bounds__(256, 2) void hexconv_kernel(
        const float* __restrict__ x, const float* __restrict__ bias,
        const unsigned short* __restrict__ wsA, float* __restrict__ out) {
    __shared__ unsigned short Xs[NPIX * PIXSTRIDE];
    const int b   = blockIdx.x;
    const int tid = threadIdx.x;
    const int lane = tid & 63, wv = tid >> 6;
    const int lr = lane & 15, lq = lane >> 4;
    const float* xb = x + (size_t)b * 64 * 169;

    const int ctp = wv & 1;
    const int nth = wv >> 1;

    const unsigned short* wA = wsA + (size_t)((ctp*2*14)*64 + lane)*8;
    // ks=0 fragments issued before staging; only 32 VGPRs held
    short8 a0 = *(const short8*)(wA);
    short8 a1 = *(const short8*)(wA + 14*64*8);

    // ---- staging: lane <-> pixel, wave <-> 16-channel block ----
    int sp[4];
    #pragma unroll
    for (int pi = 0; pi < 4; ++pi) sp[pi] = c_map.m[lane + 64*pi];

    #pragma unroll
    for (int pi = 0; pi < 4; ++pi) {
        int pix = lane + 64*pi;
        if (pix < NPIX) {
            const int s = sp[pi];
            uint32_t pk[8];
            #pragma unroll
            for (int h = 0; h < 8; ++h) {
                int ci = wv*16 + 2*h;
                float v0 = (s >= 0) ? xb[ci*169 + s]     : 0.f;
                float v1 = (s >= 0) ? xb[(ci+1)*169 + s] : 0.f;
                uint32_t u0 = __float_as_uint(v0) + 0x8000u;   // round-half-up bf16
                uint32_t u1 = __float_as_uint(v1) + 0x8000u;
                pk[h] = __builtin_amdgcn_perm(u1, u0, 0x07060302u); // hi16|hi16
            }
            unsigned short* dst = &Xs[pix*PIXSTRIDE + wv*16];
            #pragma unroll
            for (int q = 0; q < 4; ++q) {
                uint64_t w2 = (uint64_t)pk[2*q] | ((uint64_t)pk[2*q+1] << 32);
                *(uint64_t*)(dst + q*4) = w2;   // 8B-aligned, 2-way (free) banks
            }
        }
    }
    __syncthreads();

    // ---- main loop: LDS b64 pairs + MFMA, A prefetched one ks ahead ----
    float4v acc[2][7];
    #pragma unroll
    for (int c = 0; c < 2; ++c)
        #pragma unroll
        for (int j = 0; j < 7; ++j)
            acc[c][j] = float4v{0.f, 0.f, 0.f, 0.f};

    const int offs[7] = {0,1,15,16,17,31,32};   // ti*15+tj for the 7 hex taps
    #pragma unroll
    for (int ks = 0; ks < 14; ++ks) {
        short8 a0n = a0, a1n = a1;
        if (ks < 13) {
            a0n = *(const short8*)(wA + (size_t)(ks+1)*64*8);
            a1n = *(const short8*)(wA + (size_t)(14 + ks+1)*64*8);
        }
        const int tap = ks >> 1;                 // k-step never straddles a tap
        const int cib = (ks & 1)*32 + lq*8;
        #pragma unroll
        for (int j = 0; j < 7; ++j) {
            int nt = nth*7 + j;
            if (nt < 13) {
                int pixb = nt*16 + lr + offs[tap];
                const unsigned short* p = &Xs[pixb*PIXSTRIDE + cib];
                union { short8 v; uint64_t q[2]; } u;
                u.q[0] = *(const uint64_t*)p;
                u.q[1] = *(const uint64_t*)(p + 4);
                acc[0][j] = __builtin_amdgcn_mfma_f32_16x16x32_bf16(a0, u.v, acc[0][j], 0, 0, 0);
                acc[1][j] = __builtin_amdgcn_mfma_f32_16x16x32_bf16(a1, u.v, acc[1][j], 0, 0, 0);
            }
        }
        a0 = a0n; a1 = a1n;
    }

    // ---- epilogue: row co = ct*16 + lq*4 + r, col p15 = nt*16 + lr ----
    #pragma unroll
    for (int j = 0; j < 7; ++j) {
        int nt = nth*7 + j;
        if (nt >= 13) continue;
        int p15 = nt*16 + lr;
        int y = p15 / 15, xc = p15 % 15;
        if (xc >= 13 || y >= 13) continue;
        float omv = c_om.v[y*13 + xc];
        size_t obase = (size_t)b*64*169 + y*13 + xc;
        #pragma unroll
        for (int c = 0; c < 2; ++c) {
            int ct = ctp*2 + c;
            #pragma unroll
            for (int r = 0; r < 4; ++r) {
                int co = ct*16 + lq*4 + r;
                out[obase + (size_t)co*169] = (acc[c][j][r] + bias[co]) * omv;
            }
        }
    }
}

extern "C" void kernel_launch(void* const* d_in, const int* in_sizes, int n_in,
                              void* d_out, int out_size, void* d_ws, size_t ws_size,
                              hipStream_t stream) {
    const float* x    = (const float*)d_in[0];
    const float* w    = (const float*)d_in[1];
    const float* bias = (const float*)d_in[2];
    float* out = (float*)d_out;

    unsigned short* wsA = (unsigned short*)d_ws;

    hex_prep_kernel<<<16, 256, 0, stream>>>(w, wsA);

    int B = in_sizes[0] / (64 * 169);   // 4096 images
    hexconv_kernel<<<B, 256, 0, stream>>>(x, bias, wsA, out);
}